// Round 1
// baseline (13858.434 us; speedup 1.0000x reference)
//
#include <hip/hip_runtime.h>
#include <hip/hip_bf16.h>

// ---------------------------------------------------------------------------
// GNN: 3 message-passing steps + readout. fp32, VALU implementation.
// Layout choice: wave-per-edge (lane = output channel), K-broadcast via
// v_readlane (SGPR operand), first-layer weights in LDS, hidden weights in
// per-lane VGPRs. Structured so edge/node MLPs can later become bf16 MFMA.
// ---------------------------------------------------------------------------

__device__ __forceinline__ float readlane_f(float v, int l) {
    return __uint_as_float(__builtin_amdgcn_readlane(__float_as_uint(v), l));
}

__device__ __forceinline__ float gelu(float x) {
    // jax.nn.gelu approximate=True (tanh form)
    float x3 = x * x * x;
    return 0.5f * x * (1.f + tanhf(0.7978845608028654f * (x + 0.044715f * x3)));
}

// accumulate one 64-wide chunk of layer-1: acc[h] += sum_k src_lane_k * W[k][h]
__device__ __forceinline__ void acc64_lds(float src, const float* sw, int lane,
                                          float acc[4]) {
#pragma unroll
    for (int k = 0; k < 64; ++k) {
        float v = readlane_f(src, k);
        acc[k & 3] = fmaf(v, sw[k * 64 + lane], acc[k & 3]);
    }
}

// 64-dot with per-lane register weight column: out[h] = b + sum_k src_k * w[k]
__device__ __forceinline__ float dot64_reg(float src, const float (&w)[64],
                                           float bias) {
    float acc[4] = {bias, 0.f, 0.f, 0.f};
#pragma unroll
    for (int k = 0; k < 64; ++k) {
        float v = readlane_f(src, k);
        acc[k & 3] = fmaf(v, w[k], acc[k & 3]);
    }
    return (acc[0] + acc[1]) + (acc[2] + acc[3]);
}

__device__ __forceinline__ float wave_ln(float v, float lns, float lnb) {
    float s1 = v, s2 = v * v;
#pragma unroll
    for (int m = 32; m; m >>= 1) {
        s1 += __shfl_xor(s1, m, 64);
        s2 += __shfl_xor(s2, m, 64);
    }
    float mu = s1 * (1.f / 64.f);
    float var = s2 * (1.f / 64.f) - mu * mu;
    return (v - mu) * rsqrtf(var + 1e-6f) * lns + lnb;
}

// ---------------------------------------------------------------------------
__global__ void k_embed(const float* __restrict__ nodes,
                        const float* __restrict__ W, const float* __restrict__ b,
                        float* __restrict__ x, int n) {
    int lane = threadIdx.x & 63;
    int wid = blockIdx.x * 4 + (threadIdx.x >> 6);
    int nw = gridDim.x * 4;
    float wcol[7];
#pragma unroll
    for (int k = 0; k < 7; ++k) wcol[k] = W[k * 64 + lane];
    float bh = b[lane];
    for (int v = wid; v < n; v += nw) {
        float acc = bh;
#pragma unroll
        for (int k = 0; k < 7; ++k) acc = fmaf(nodes[v * 7 + k], wcol[k], acc);
        x[(size_t)v * 64 + lane] = acc;
    }
}

// ---------------------------------------------------------------------------
// Edge MLP + scatter-add + LN.  KIN = 128 (step 0) or 192 (steps 1,2).
// e_in = [prev?, sent, recv]; edges updated in-place (read own row first).
template <int KIN>
__global__ __launch_bounds__(256, 2) void k_edge(
    const float* __restrict__ x, float* __restrict__ edges,
    const int* __restrict__ senders, const int* __restrict__ receivers,
    const float* __restrict__ W0, const float* __restrict__ Wh1,
    const float* __restrict__ Wh2, const float* __restrict__ b0,
    const float* __restrict__ b1, const float* __restrict__ b2,
    const float* __restrict__ ln_s, const float* __restrict__ ln_b,
    float* __restrict__ received, int n_edges) {
    __shared__ float sW0[KIN * 64];
    int tid = threadIdx.x;
    for (int i = tid; i < KIN * 64; i += 256) sW0[i] = W0[i];
    __syncthreads();

    int lane = tid & 63;
    float wh1[64], wh2[64];
#pragma unroll
    for (int k = 0; k < 64; ++k) wh1[k] = Wh1[k * 64 + lane];
#pragma unroll
    for (int k = 0; k < 64; ++k) wh2[k] = Wh2[k * 64 + lane];
    float b0h = b0[lane], b1h = b1[lane], b2h = b2[lane];
    float lns = ln_s[lane], lnb = ln_b[lane];

    int wsub = __builtin_amdgcn_readfirstlane(tid >> 6);
    int wid = blockIdx.x * 4 + wsub;
    int nw = gridDim.x * 4;

    for (int e = wid; e < n_edges; e += nw) {
        int snd = senders[e];
        int rcv = receivers[e];
        float sent = x[(size_t)snd * 64 + lane];
        float recv = x[(size_t)rcv * 64 + lane];

        float acc[4] = {b0h, 0.f, 0.f, 0.f};
        if constexpr (KIN == 192) {
            float prev = edges[(size_t)e * 64 + lane];
            acc64_lds(prev, sW0, lane, acc);
            acc64_lds(sent, sW0 + 64 * 64, lane, acc);
            acc64_lds(recv, sW0 + 128 * 64, lane, acc);
        } else {
            acc64_lds(sent, sW0, lane, acc);
            acc64_lds(recv, sW0 + 64 * 64, lane, acc);
        }
        float a1 = gelu((acc[0] + acc[1]) + (acc[2] + acc[3]));
        float a2 = gelu(dot64_reg(a1, wh1, b1h));
        float eraw = dot64_reg(a2, wh2, b2h);

        // segment_sum uses PRE-layernorm edges
        atomicAdd(&received[(size_t)rcv * 64 + lane], eraw);

        edges[(size_t)e * 64 + lane] = wave_ln(eraw, lns, lnb);
    }
}

// ---------------------------------------------------------------------------
// Node MLP + LN.  n_in = [x, received] (128 wide).
__global__ __launch_bounds__(256, 2) void k_node(
    const float* __restrict__ x, const float* __restrict__ received,
    const float* __restrict__ W0, const float* __restrict__ Wh1,
    const float* __restrict__ Wh2, const float* __restrict__ b0,
    const float* __restrict__ b1, const float* __restrict__ b2,
    const float* __restrict__ ln_s, const float* __restrict__ ln_b,
    float* __restrict__ xout, int n) {
    __shared__ float sW0[128 * 64];
    int tid = threadIdx.x;
    for (int i = tid; i < 128 * 64; i += 256) sW0[i] = W0[i];
    __syncthreads();

    int lane = tid & 63;
    float wh1[64], wh2[64];
#pragma unroll
    for (int k = 0; k < 64; ++k) wh1[k] = Wh1[k * 64 + lane];
#pragma unroll
    for (int k = 0; k < 64; ++k) wh2[k] = Wh2[k * 64 + lane];
    float b0h = b0[lane], b1h = b1[lane], b2h = b2[lane];
    float lns = ln_s[lane], lnb = ln_b[lane];

    int wsub = __builtin_amdgcn_readfirstlane(tid >> 6);
    int wid = blockIdx.x * 4 + wsub;
    int nw = gridDim.x * 4;

    for (int v = wid; v < n; v += nw) {
        float xv = x[(size_t)v * 64 + lane];
        float rv = received[(size_t)v * 64 + lane];

        float acc[4] = {b0h, 0.f, 0.f, 0.f};
        acc64_lds(xv, sW0, lane, acc);
        acc64_lds(rv, sW0 + 64 * 64, lane, acc);
        float a1 = gelu((acc[0] + acc[1]) + (acc[2] + acc[3]));
        float a2 = gelu(dot64_reg(a1, wh1, b1h));
        float v3 = dot64_reg(a2, wh2, b2h);

        xout[(size_t)v * 64 + lane] = wave_ln(v3, lns, lnb);
    }
}

// ---------------------------------------------------------------------------
__global__ void k_mean(const float* __restrict__ x, float* __restrict__ agg,
                       int n) {
    int t = threadIdx.x;
    int h = t & 63;
    int sub = t >> 6;
    float s = 0.f;
    for (int v = blockIdx.x * 4 + sub; v < n; v += gridDim.x * 4)
        s += x[(size_t)v * 64 + h];
    __shared__ float buf[256];
    buf[t] = s;
    __syncthreads();
    if (t < 64) {
        float tot = buf[t] + buf[t + 64] + buf[t + 128] + buf[t + 192];
        atomicAdd(&agg[h], tot);
    }
}

__global__ void k_readout(const float* __restrict__ agg,
                          const float* __restrict__ W1, const float* __restrict__ b1,
                          const float* __restrict__ W2, const float* __restrict__ b2,
                          const float* __restrict__ W3, const float* __restrict__ b3,
                          const float* __restrict__ W4, const float* __restrict__ b4,
                          float* __restrict__ out, float inv_n) {
    __shared__ float sA[64], sH1[256], sH2[128], sH3[128];
    int t = threadIdx.x;
    if (t < 64) sA[t] = agg[t] * inv_n;
    __syncthreads();
    {
        float acc = b1[t];
#pragma unroll
        for (int k = 0; k < 64; ++k) acc = fmaf(sA[k], W1[k * 256 + t], acc);
        sH1[t] = gelu(acc);
    }
    __syncthreads();
    if (t < 128) {
        float acc = b2[t];
        for (int k = 0; k < 256; ++k) acc = fmaf(sH1[k], W2[k * 128 + t], acc);
        sH2[t] = gelu(acc);
    }
    __syncthreads();
    if (t < 128) {
        float acc = b3[t];
        for (int k = 0; k < 128; ++k) acc = fmaf(sH2[k], W3[k * 128 + t], acc);
        sH3[t] = gelu(acc);
    }
    __syncthreads();
    if (t < 64) {
        float p = fmaf(sH3[t], W4[t], sH3[t + 64] * W4[t + 64]);
#pragma unroll
        for (int m = 32; m; m >>= 1) p += __shfl_xor(p, m, 64);
        if (t == 0) out[0] = p + b4[0];
    }
}

// ---------------------------------------------------------------------------
extern "C" void kernel_launch(void* const* d_in, const int* in_sizes, int n_in,
                              void* d_out, int out_size, void* d_ws,
                              size_t ws_size, hipStream_t stream) {
    const float* nodes = (const float*)d_in[0];
    const int* senders = (const int*)d_in[1];
    const int* receivers = (const int*)d_in[2];
    const float* W_emb = (const float*)d_in[3];
    const float* b_emb = (const float*)d_in[4];
    const float* eW0_first = (const float*)d_in[5];
    const float* eW0_rest = (const float*)d_in[6];
    const float* eW_hid = (const float*)d_in[7];
    const float* eb = (const float*)d_in[8];
    const float* nW0 = (const float*)d_in[9];
    const float* nW_hid = (const float*)d_in[10];
    const float* nb = (const float*)d_in[11];
    const float* ln_ns = (const float*)d_in[12];
    const float* ln_nb = (const float*)d_in[13];
    const float* ln_es = (const float*)d_in[14];
    const float* ln_eb = (const float*)d_in[15];
    const float* rW1 = (const float*)d_in[16];
    const float* rb1 = (const float*)d_in[17];
    const float* rW2 = (const float*)d_in[18];
    const float* rb2 = (const float*)d_in[19];
    const float* rW3 = (const float*)d_in[20];
    const float* rb3 = (const float*)d_in[21];
    const float* rW4 = (const float*)d_in[22];
    const float* rb4 = (const float*)d_in[23];

    const int N = in_sizes[0] / 7;  // 50000
    const int E = in_sizes[1];      // 800000

    float* ws = (float*)d_ws;
    float* edges = ws;                            // E*64
    float* xa = edges + (size_t)E * 64;           // N*64
    float* xb = xa + (size_t)N * 64;              // N*64
    float* received = xb + (size_t)N * 64;        // N*64
    float* agg = received + (size_t)N * 64;       // 64

    k_embed<<<512, 256, 0, stream>>>(nodes, W_emb, b_emb, xa, N);

    float* xc = xa;
    float* xn = xb;
    for (int s = 0; s < 3; ++s) {
        hipMemsetAsync(received, 0, (size_t)N * 64 * sizeof(float), stream);
        const float* Wh1 = eW_hid + (size_t)(s * 2 + 0) * 4096;
        const float* Wh2 = eW_hid + (size_t)(s * 2 + 1) * 4096;
        const float* eb0 = eb + (s * 3 + 0) * 64;
        const float* eb1 = eb + (s * 3 + 1) * 64;
        const float* eb2 = eb + (s * 3 + 2) * 64;
        if (s == 0) {
            k_edge<128><<<512, 256, 0, stream>>>(
                xc, edges, senders, receivers, eW0_first, Wh1, Wh2, eb0, eb1,
                eb2, ln_es + s * 64, ln_eb + s * 64, received, E);
        } else {
            k_edge<192><<<512, 256, 0, stream>>>(
                xc, edges, senders, receivers, eW0_rest + (size_t)(s - 1) * 192 * 64,
                Wh1, Wh2, eb0, eb1, eb2, ln_es + s * 64, ln_eb + s * 64,
                received, E);
        }
        k_node<<<512, 256, 0, stream>>>(
            xc, received, nW0 + (size_t)s * 128 * 64,
            nW_hid + (size_t)(s * 2 + 0) * 4096,
            nW_hid + (size_t)(s * 2 + 1) * 4096, nb + (s * 3 + 0) * 64,
            nb + (s * 3 + 1) * 64, nb + (s * 3 + 2) * 64, ln_ns + s * 64,
            ln_nb + s * 64, xn, N);
        float* tmp = xc;
        xc = xn;
        xn = tmp;
    }

    hipMemsetAsync(agg, 0, 64 * sizeof(float), stream);
    k_mean<<<256, 256, 0, stream>>>(xc, agg, N);
    k_readout<<<1, 256, 0, stream>>>(agg, rW1, rb1, rW2, rb2, rW3, rb3, rW4,
                                     rb4, (float*)d_out, 1.0f / (float)N);
}

// Round 10
// 5757.728 us; speedup vs baseline: 2.4069x; 2.4069x over previous
//
#include <hip/hip_runtime.h>
#include <hip/hip_bf16.h>

// ---------------------------------------------------------------------------
// GNN: 3 message-passing steps + readout. fp32 VALU implementation, round 2
// kernel (resubmitted unchanged; infra failures rounds 2-9).
// Changes vs round 1 (which was fetch-bound at 10.4 GB/dispatch):
//  - segment_sum via CSR gather (hist/scan/fill built per call) instead of
//    51.2M fp32 atomics -> removes ~6.5 GB/step of atomic line-fetch traffic.
//  - edge kernel stores RAW edge outputs; LayerNorm is applied lazily when
//    the next step's edge MLP reads the row (aggregation is pre-LN per the
//    reference; step-2 edge LN is dead code and skipped entirely).
//  - __launch_bounds__(256) without min-wave clamp: r1's VGPR=128 cap forced
//    spills (needs ~150 live regs) whose reloads showed up as FETCH traffic.
// Workspace audit: ~234 MB < round-1's 243 MB which ran fine.
// Model: KIN=192 k_edge floor ~417us VALU (640 wave-insts/edge), LDS ~250us
// (not the bound). Next lever after validation: split-bf16 MFMA GEMMs
// (A/B frag k-layout hypothesis: k = 4*(l>>4) + (i&3) + 16*(i>>2), from
// m156 tr_b16 mapping; C/D verified col=lane&15,row=(lane>>4)*4+reg).
// ---------------------------------------------------------------------------

__device__ __forceinline__ float readlane_f(float v, int l) {
    return __uint_as_float(__builtin_amdgcn_readlane(__float_as_uint(v), l));
}

__device__ __forceinline__ float gelu(float x) {
    float x3 = x * x * x;
    return 0.5f * x * (1.f + tanhf(0.7978845608028654f * (x + 0.044715f * x3)));
}

// acc[h] += sum_k src_lane_k * W[k][h], W staged in LDS (stride-1 in h)
__device__ __forceinline__ void acc64_lds(float src, const float* sw, int lane,
                                          float acc[4]) {
#pragma unroll
    for (int k = 0; k < 64; ++k) {
        float v = readlane_f(src, k);
        acc[k & 3] = fmaf(v, sw[k * 64 + lane], acc[k & 3]);
    }
}

// out[h] = b + sum_k src_k * w[k], weight column in per-lane VGPRs
__device__ __forceinline__ float dot64_reg(float src, const float (&w)[64],
                                           float bias) {
    float acc[4] = {bias, 0.f, 0.f, 0.f};
#pragma unroll
    for (int k = 0; k < 64; ++k) {
        float v = readlane_f(src, k);
        acc[k & 3] = fmaf(v, w[k], acc[k & 3]);
    }
    return (acc[0] + acc[1]) + (acc[2] + acc[3]);
}

__device__ __forceinline__ float wave_ln(float v, float lns, float lnb) {
    float s1 = v, s2 = v * v;
#pragma unroll
    for (int m = 32; m; m >>= 1) {
        s1 += __shfl_xor(s1, m, 64);
        s2 += __shfl_xor(s2, m, 64);
    }
    float mu = s1 * (1.f / 64.f);
    float var = s2 * (1.f / 64.f) - mu * mu;
    return (v - mu) * rsqrtf(var + 1e-6f) * lns + lnb;
}

// ---------------------------------------------------------------------------
// CSR construction: hist -> 2-level exclusive scan -> fill
__global__ void k_hist(const int* __restrict__ receivers, int* __restrict__ cnt,
                       int nE) {
    int e = blockIdx.x * blockDim.x + threadIdx.x;
    if (e < nE) atomicAdd(&cnt[receivers[e]], 1);
}

__global__ void k_scan1(const int* __restrict__ cnt, int* __restrict__ bsum,
                        int n) {
    __shared__ int sb[256];
    int t = threadIdx.x;
    int i = blockIdx.x * 256 + t;
    sb[t] = (i < n) ? cnt[i] : 0;
    __syncthreads();
    for (int off = 128; off; off >>= 1) {
        if (t < off) sb[t] += sb[t + off];
        __syncthreads();
    }
    if (t == 0) bsum[blockIdx.x] = sb[0];
}

__global__ void k_scan2(int* __restrict__ bsum, int nb) {
    __shared__ int sb[256];
    int t = threadIdx.x;
    int v = (t < nb) ? bsum[t] : 0;
    sb[t] = v;
    __syncthreads();
    for (int off = 1; off < 256; off <<= 1) {
        int add = (t >= off) ? sb[t - off] : 0;
        __syncthreads();
        sb[t] += add;
        __syncthreads();
    }
    if (t < nb) bsum[t] = sb[t] - v;  // exclusive
}

__global__ void k_scan3(const int* __restrict__ cnt, const int* __restrict__ bsum,
                        int* __restrict__ row_start, int* __restrict__ cursor,
                        int n, int nE) {
    __shared__ int sb[256];
    int t = threadIdx.x;
    int i = blockIdx.x * 256 + t;
    int v = (i < n) ? cnt[i] : 0;
    sb[t] = v;
    __syncthreads();
    for (int off = 1; off < 256; off <<= 1) {
        int add = (t >= off) ? sb[t - off] : 0;
        __syncthreads();
        sb[t] += add;
        __syncthreads();
    }
    if (i < n) {
        int ex = bsum[blockIdx.x] + sb[t] - v;
        row_start[i] = ex;
        cursor[i] = ex;
    }
    if (i == n - 1) row_start[n] = nE;
}

__global__ void k_fill(const int* __restrict__ receivers, int* __restrict__ cursor,
                       int* __restrict__ elist, int nE) {
    int e = blockIdx.x * blockDim.x + threadIdx.x;
    if (e < nE) {
        int r = receivers[e];
        int p = atomicAdd(&cursor[r], 1);
        elist[p] = e;
    }
}

// ---------------------------------------------------------------------------
__global__ void k_embed(const float* __restrict__ nodes,
                        const float* __restrict__ W, const float* __restrict__ b,
                        float* __restrict__ x, int n) {
    int lane = threadIdx.x & 63;
    int wid = blockIdx.x * 4 + (threadIdx.x >> 6);
    int nw = gridDim.x * 4;
    float wcol[7];
#pragma unroll
    for (int k = 0; k < 7; ++k) wcol[k] = W[k * 64 + lane];
    float bh = b[lane];
    for (int v = wid; v < n; v += nw) {
        float acc = bh;
#pragma unroll
        for (int k = 0; k < 7; ++k) acc = fmaf(nodes[v * 7 + k], wcol[k], acc);
        x[(size_t)v * 64 + lane] = acc;
    }
}

// ---------------------------------------------------------------------------
// Edge MLP. KIN = 128 (step 0) or 192 (steps 1,2). Writes RAW (pre-LN) edge
// output in-place. For KIN=192, the previous step's LN is applied on read.
template <int KIN>
__global__ __launch_bounds__(256) void k_edge(
    const float* __restrict__ x, float* __restrict__ eraw,
    const int* __restrict__ senders, const int* __restrict__ receivers,
    const float* __restrict__ W0, const float* __restrict__ Wh1,
    const float* __restrict__ Wh2, const float* __restrict__ b0,
    const float* __restrict__ b1, const float* __restrict__ b2,
    const float* __restrict__ lnp_s, const float* __restrict__ lnp_b,
    int n_edges) {
    __shared__ float sW0[KIN * 64];
    int tid = threadIdx.x;
    for (int i = tid; i < KIN * 64; i += 256) sW0[i] = W0[i];
    __syncthreads();

    int lane = tid & 63;
    float wh1[64], wh2[64];
#pragma unroll
    for (int k = 0; k < 64; ++k) wh1[k] = Wh1[k * 64 + lane];
#pragma unroll
    for (int k = 0; k < 64; ++k) wh2[k] = Wh2[k * 64 + lane];
    float b0h = b0[lane], b1h = b1[lane], b2h = b2[lane];
    float plns = 0.f, plnb = 0.f;
    if constexpr (KIN == 192) {
        plns = lnp_s[lane];
        plnb = lnp_b[lane];
    }

    int wsub = __builtin_amdgcn_readfirstlane(tid >> 6);
    int wid = blockIdx.x * 4 + wsub;
    int nw = gridDim.x * 4;

    for (int e = wid; e < n_edges; e += nw) {
        int snd = senders[e];
        int rcv = receivers[e];
        float sent = x[(size_t)snd * 64 + lane];
        float recv = x[(size_t)rcv * 64 + lane];

        float acc[4] = {b0h, 0.f, 0.f, 0.f};
        if constexpr (KIN == 192) {
            float prev = wave_ln(eraw[(size_t)e * 64 + lane], plns, plnb);
            acc64_lds(prev, sW0, lane, acc);
            acc64_lds(sent, sW0 + 64 * 64, lane, acc);
            acc64_lds(recv, sW0 + 128 * 64, lane, acc);
        } else {
            acc64_lds(sent, sW0, lane, acc);
            acc64_lds(recv, sW0 + 64 * 64, lane, acc);
        }
        float a1 = gelu((acc[0] + acc[1]) + (acc[2] + acc[3]));
        float a2 = gelu(dot64_reg(a1, wh1, b1h));
        eraw[(size_t)e * 64 + lane] = dot64_reg(a2, wh2, b2h);
    }
}

// ---------------------------------------------------------------------------
// Node update: CSR gather-sum of raw edges, then node MLP + LN.
__global__ __launch_bounds__(256) void k_node(
    const float* __restrict__ x, const float* __restrict__ eraw,
    const int* __restrict__ row_start, const int* __restrict__ elist,
    const float* __restrict__ W0, const float* __restrict__ Wh1,
    const float* __restrict__ Wh2, const float* __restrict__ b0,
    const float* __restrict__ b1, const float* __restrict__ b2,
    const float* __restrict__ ln_s, const float* __restrict__ ln_b,
    float* __restrict__ xout, int n) {
    __shared__ float sW0[128 * 64];
    int tid = threadIdx.x;
    for (int i = tid; i < 128 * 64; i += 256) sW0[i] = W0[i];
    __syncthreads();

    int lane = tid & 63;
    float wh1[64], wh2[64];
#pragma unroll
    for (int k = 0; k < 64; ++k) wh1[k] = Wh1[k * 64 + lane];
#pragma unroll
    for (int k = 0; k < 64; ++k) wh2[k] = Wh2[k * 64 + lane];
    float b0h = b0[lane], b1h = b1[lane], b2h = b2[lane];
    float lns = ln_s[lane], lnb = ln_b[lane];

    int wsub = __builtin_amdgcn_readfirstlane(tid >> 6);
    int wid = blockIdx.x * 4 + wsub;
    int nw = gridDim.x * 4;

    for (int v = wid; v < n; v += nw) {
        float xv = x[(size_t)v * 64 + lane];
        int i0 = row_start[v], i1 = row_start[v + 1];

        float rv = 0.f, rv2 = 0.f;
        int i = i0;
        for (; i + 1 < i1; i += 2) {
            int e0 = elist[i], e1 = elist[i + 1];
            rv += eraw[(size_t)e0 * 64 + lane];
            rv2 += eraw[(size_t)e1 * 64 + lane];
        }
        if (i < i1) rv += eraw[(size_t)elist[i] * 64 + lane];
        rv += rv2;

        float acc[4] = {b0h, 0.f, 0.f, 0.f};
        acc64_lds(xv, sW0, lane, acc);
        acc64_lds(rv, sW0 + 64 * 64, lane, acc);
        float a1 = gelu((acc[0] + acc[1]) + (acc[2] + acc[3]));
        float a2 = gelu(dot64_reg(a1, wh1, b1h));
        float v3 = dot64_reg(a2, wh2, b2h);

        xout[(size_t)v * 64 + lane] = wave_ln(v3, lns, lnb);
    }
}

// ---------------------------------------------------------------------------
__global__ void k_mean(const float* __restrict__ x, float* __restrict__ agg,
                       int n) {
    int t = threadIdx.x;
    int h = t & 63;
    int sub = t >> 6;
    float s = 0.f;
    for (int v = blockIdx.x * 4 + sub; v < n; v += gridDim.x * 4)
        s += x[(size_t)v * 64 + h];
    __shared__ float buf[256];
    buf[t] = s;
    __syncthreads();
    if (t < 64) {
        float tot = buf[t] + buf[t + 64] + buf[t + 128] + buf[t + 192];
        atomicAdd(&agg[h], tot);
    }
}

__global__ void k_readout(const float* __restrict__ agg,
                          const float* __restrict__ W1, const float* __restrict__ b1,
                          const float* __restrict__ W2, const float* __restrict__ b2,
                          const float* __restrict__ W3, const float* __restrict__ b3,
                          const float* __restrict__ W4, const float* __restrict__ b4,
                          float* __restrict__ out, float inv_n) {
    __shared__ float sA[64], sH1[256], sH2[128], sH3[128];
    int t = threadIdx.x;
    if (t < 64) sA[t] = agg[t] * inv_n;
    __syncthreads();
    {
        float acc = b1[t];
#pragma unroll
        for (int k = 0; k < 64; ++k) acc = fmaf(sA[k], W1[k * 256 + t], acc);
        sH1[t] = gelu(acc);
    }
    __syncthreads();
    if (t < 128) {
        float acc = b2[t];
        for (int k = 0; k < 256; ++k) acc = fmaf(sH1[k], W2[k * 128 + t], acc);
        sH2[t] = gelu(acc);
    }
    __syncthreads();
    if (t < 128) {
        float acc = b3[t];
        for (int k = 0; k < 128; ++k) acc = fmaf(sH2[k], W3[k * 128 + t], acc);
        sH3[t] = gelu(acc);
    }
    __syncthreads();
    if (t < 64) {
        float p = fmaf(sH3[t], W4[t], sH3[t + 64] * W4[t + 64]);
#pragma unroll
        for (int m = 32; m; m >>= 1) p += __shfl_xor(p, m, 64);
        if (t == 0) out[0] = p + b4[0];
    }
}

// ---------------------------------------------------------------------------
extern "C" void kernel_launch(void* const* d_in, const int* in_sizes, int n_in,
                              void* d_out, int out_size, void* d_ws,
                              size_t ws_size, hipStream_t stream) {
    const float* nodes = (const float*)d_in[0];
    const int* senders = (const int*)d_in[1];
    const int* receivers = (const int*)d_in[2];
    const float* W_emb = (const float*)d_in[3];
    const float* b_emb = (const float*)d_in[4];
    const float* eW0_first = (const float*)d_in[5];
    const float* eW0_rest = (const float*)d_in[6];
    const float* eW_hid = (const float*)d_in[7];
    const float* eb = (const float*)d_in[8];
    const float* nW0 = (const float*)d_in[9];
    const float* nW_hid = (const float*)d_in[10];
    const float* nb = (const float*)d_in[11];
    const float* ln_ns = (const float*)d_in[12];
    const float* ln_nb = (const float*)d_in[13];
    const float* ln_es = (const float*)d_in[14];
    const float* ln_eb = (const float*)d_in[15];
    const float* rW1 = (const float*)d_in[16];
    const float* rb1 = (const float*)d_in[17];
    const float* rW2 = (const float*)d_in[18];
    const float* rb2 = (const float*)d_in[19];
    const float* rW3 = (const float*)d_in[20];
    const float* rb3 = (const float*)d_in[21];
    const float* rW4 = (const float*)d_in[22];
    const float* rb4 = (const float*)d_in[23];

    const int N = in_sizes[0] / 7;  // 50000
    const int E = in_sizes[1];      // 800000

    float* ws = (float*)d_ws;
    float* eraw = ws;                         // E*64
    float* xa = eraw + (size_t)E * 64;        // N*64
    float* xb = xa + (size_t)N * 64;          // N*64
    float* agg = xb + (size_t)N * 64;         // 64
    int* cnt = (int*)(agg + 64);              // N
    int* row_start = cnt + N;                 // N+1
    int* cursor = row_start + N + 1;          // N
    int* elist = cursor + N;                  // E
    int* bsum = elist + E;                    // 256

    const int nb_scan = (N + 255) / 256;  // 196

    // ---- CSR build (receivers are the same for all 3 steps) ----
    hipMemsetAsync(cnt, 0, (size_t)N * sizeof(int), stream);
    k_hist<<<(E + 255) / 256, 256, 0, stream>>>(receivers, cnt, E);
    k_scan1<<<nb_scan, 256, 0, stream>>>(cnt, bsum, N);
    k_scan2<<<1, 256, 0, stream>>>(bsum, nb_scan);
    k_scan3<<<nb_scan, 256, 0, stream>>>(cnt, bsum, row_start, cursor, N, E);
    k_fill<<<(E + 255) / 256, 256, 0, stream>>>(receivers, cursor, elist, E);

    k_embed<<<512, 256, 0, stream>>>(nodes, W_emb, b_emb, xa, N);

    float* xc = xa;
    float* xn = xb;
    for (int s = 0; s < 3; ++s) {
        const float* Wh1 = eW_hid + (size_t)(s * 2 + 0) * 4096;
        const float* Wh2 = eW_hid + (size_t)(s * 2 + 1) * 4096;
        const float* eb0 = eb + (s * 3 + 0) * 64;
        const float* eb1 = eb + (s * 3 + 1) * 64;
        const float* eb2 = eb + (s * 3 + 2) * 64;
        if (s == 0) {
            k_edge<128><<<512, 256, 0, stream>>>(
                xc, eraw, senders, receivers, eW0_first, Wh1, Wh2, eb0, eb1,
                eb2, nullptr, nullptr, E);
        } else {
            // previous step's edge LN applied on read
            k_edge<192><<<512, 256, 0, stream>>>(
                xc, eraw, senders, receivers,
                eW0_rest + (size_t)(s - 1) * 192 * 64, Wh1, Wh2, eb0, eb1, eb2,
                ln_es + (s - 1) * 64, ln_eb + (s - 1) * 64, E);
        }
        k_node<<<512, 256, 0, stream>>>(
            xc, eraw, row_start, elist, nW0 + (size_t)s * 128 * 64,
            nW_hid + (size_t)(s * 2 + 0) * 4096,
            nW_hid + (size_t)(s * 2 + 1) * 4096, nb + (s * 3 + 0) * 64,
            nb + (s * 3 + 1) * 64, nb + (s * 3 + 2) * 64, ln_ns + s * 64,
            ln_nb + s * 64, xn, N);
        float* tmp = xc;
        xc = xn;
        xn = tmp;
    }

    hipMemsetAsync(agg, 0, 64 * sizeof(float), stream);
    k_mean<<<256, 256, 0, stream>>>(xc, agg, N);
    k_readout<<<1, 256, 0, stream>>>(agg, rW1, rb1, rW2, rb2, rW3, rb3, rW4,
                                     rb4, (float*)d_out, 1.0f / (float)N);
}

// Round 11
// 4220.204 us; speedup vs baseline: 3.2838x; 1.3643x over previous
//
#include <hip/hip_runtime.h>
#include <hip/hip_bf16.h>

// ---------------------------------------------------------------------------
// GNN round 11: MFMA (bf16x3 split ~= fp32) for edge/node MLP GEMMs.
// r10 counters: k_edge<192> = 1879us, VALUBusy 48%, MfmaUtil 0, FETCH 290MB.
// LDS model: 192 ds_read_b32/edge @5.8cyc = ~1450us -> LDS-issue-bound.
// Fix: per-wave 16-row MFMA tiles. A staged fp32 in LDS (padded, b128 reads),
// split hi/mid/lo at frag assembly; B (weights) pre-split+pre-swizzled into
// fragment order by prep kernels -> coalesced dwordx4 loads, L2-hot.
// 6 MFMAs per pair (hh,hm,mh,hl,mm,lh) => error ~2^-24 (fp32-level).
// C/D layout: col=lane&15, row=(lane>>4)*4+reg (m89-verified). A/B packed
// with identical (lane,j)->k map; consistent k-permutation is contraction-
// invariant, so only the row/col maps (standard l&15) must be right.
// CSR/scan/embed/mean/readout kernels unchanged from the validated r10 base.
// ---------------------------------------------------------------------------

typedef unsigned short ushort;
typedef unsigned int uint;
using bf16x8 = __attribute__((ext_vector_type(8))) short;
using f32x4 = __attribute__((ext_vector_type(4))) float;

__device__ __forceinline__ f32x4 mfma16(bf16x8 a, bf16x8 b, f32x4 c) {
    return __builtin_amdgcn_mfma_f32_16x16x32_bf16(a, b, c, 0, 0, 0);
}

__device__ __forceinline__ ushort f2bf(float x) {  // RNE truncate to bf16 bits
    union { float f; uint u; } v;
    v.f = x;
    uint r = v.u + 0x7fffu + ((v.u >> 16) & 1u);
    return (ushort)(r >> 16);
}
__device__ __forceinline__ float bf2f(ushort u) {
    union { uint u; float f; } v;
    v.u = ((uint)u) << 16;
    return v.f;
}

__device__ __forceinline__ float gelu(float x) {
    float x3 = x * x * x;
    return 0.5f * x * (1.f + tanhf(0.7978845608028654f * (x + 0.044715f * x3)));
}

__device__ __forceinline__ float wave_ln(float v, float lns, float lnb) {
    float s1 = v, s2 = v * v;
#pragma unroll
    for (int m = 32; m; m >>= 1) {
        s1 += __shfl_xor(s1, m, 64);
        s2 += __shfl_xor(s2, m, 64);
    }
    float mu = s1 * (1.f / 64.f);
    float var = s2 * (1.f / 64.f) - mu * mu;
    return (v - mu) * rsqrtf(var + 1e-6f) * lns + lnb;
}

// ---------------------------------------------------------------------------
// Weight prep: split W[K][64] into hi/mid/lo bf16 and scatter into fragment
// order so GEMM B-frag load idx = ((kc*4+hb)*64+lane)*8+j is coalesced.
__global__ void k_prep(const float* __restrict__ W, ushort* __restrict__ dh,
                       ushort* __restrict__ dm, ushort* __restrict__ dl,
                       int K) {
    int tid = blockIdx.x * 256 + threadIdx.x;
    if (tid >= K * 64) return;
    int j = tid & 7;
    int lane = (tid >> 3) & 63;
    int hb = (tid >> 9) & 3;
    int kc = tid >> 11;
    int k = kc * 32 + 8 * (lane >> 4) + j;
    int h = hb * 16 + (lane & 15);
    float x = W[k * 64 + h];
    ushort uh = f2bf(x);
    float r = x - bf2f(uh);
    ushort um = f2bf(r);
    float r2 = r - bf2f(um);
    ushort ul = f2bf(r2);
    dh[tid] = uh;
    dm[tid] = um;
    dl[tid] = ul;
}

// ---------------------------------------------------------------------------
// One MFMA layer: D[16 rows][64] = A[16][KC*32] * B + bias(acc preloaded).
// A: fp32 in LDS, row r at Asrc[r*pad ..]; split to bf16x3 at assembly.
// B: frag-ordered global hi/mid/lo.
template <int KC>
__device__ __forceinline__ void mfma_layer(const float* Asrc, int pad,
                                           const ushort* __restrict__ Bh,
                                           const ushort* __restrict__ Bm,
                                           const ushort* __restrict__ Bl,
                                           int lane, f32x4 acc[4]) {
    int e15 = lane & 15, l4 = lane >> 4;
#pragma unroll
    for (int kc = 0; kc < KC; ++kc) {
        const float4* ap =
            reinterpret_cast<const float4*>(Asrc + e15 * pad + kc * 32 + 8 * l4);
        float4 q0 = ap[0];
        float4 q1 = ap[1];
        float av[8] = {q0.x, q0.y, q0.z, q0.w, q1.x, q1.y, q1.z, q1.w};
        bf16x8 ah, am, al;
#pragma unroll
        for (int j = 0; j < 8; ++j) {
            float v = av[j];
            ushort h = f2bf(v);
            float r = v - bf2f(h);
            ushort m = f2bf(r);
            float r2 = r - bf2f(m);
            ushort l = f2bf(r2);
            ah[j] = (short)h;
            am[j] = (short)m;
            al[j] = (short)l;
        }
#pragma unroll
        for (int hb = 0; hb < 4; ++hb) {
            int bi = ((kc * 4 + hb) * 64 + lane) * 8;
            bf16x8 bh_ = *reinterpret_cast<const bf16x8*>(Bh + bi);
            bf16x8 bm_ = *reinterpret_cast<const bf16x8*>(Bm + bi);
            bf16x8 bl_ = *reinterpret_cast<const bf16x8*>(Bl + bi);
            acc[hb] = mfma16(ah, bh_, acc[hb]);
            acc[hb] = mfma16(ah, bm_, acc[hb]);
            acc[hb] = mfma16(am, bh_, acc[hb]);
            acc[hb] = mfma16(ah, bl_, acc[hb]);
            acc[hb] = mfma16(am, bm_, acc[hb]);
            acc[hb] = mfma16(al, bh_, acc[hb]);
        }
    }
}

// ---------------------------------------------------------------------------
// Edge MLP via MFMA. KIN=128 (step 0: [sent,recv]) / 192 ([prevLN,sent,recv]).
// Per wave: tile of 16 edges. Writes RAW (pre-LN) edge output in-place.
template <int KIN>
__global__ __launch_bounds__(256) void k_edge_mfma(
    const float* __restrict__ x, float* __restrict__ eraw,
    const int* __restrict__ senders, const int* __restrict__ receivers,
    const ushort* __restrict__ B0h, const ushort* __restrict__ B0m,
    const ushort* __restrict__ B0l, const ushort* __restrict__ B1h,
    const ushort* __restrict__ B1m, const ushort* __restrict__ B1l,
    const ushort* __restrict__ B2h, const ushort* __restrict__ B2m,
    const ushort* __restrict__ B2l, const float* __restrict__ b0,
    const float* __restrict__ b1, const float* __restrict__ b2,
    const float* __restrict__ lnp_s, const float* __restrict__ lnp_b,
    int n_edges) {
    constexpr int KC0 = KIN / 32;
    constexpr int PAD0 = KIN + 8;  // 200 / 136: rows 16B-aligned, spread banks
    constexpr int PAD1 = 72;
    __shared__ float As[4][16 * PAD0];
    __shared__ float Aa[4][16 * PAD1];
    int tid = threadIdx.x;
    int lane = tid & 63;
    int wsub = tid >> 6;
    float* Aw = As[wsub];
    float* Av = Aa[wsub];
    int e15 = lane & 15, l4 = lane >> 4;

    float plns = 0.f, plnb = 0.f;
    if constexpr (KIN == 192) {
        plns = lnp_s[lane];
        plnb = lnp_b[lane];
    }
    float bv0[4], bv1[4], bv2[4];
#pragma unroll
    for (int hb = 0; hb < 4; ++hb) {
        bv0[hb] = b0[hb * 16 + e15];
        bv1[hb] = b1[hb * 16 + e15];
        bv2[hb] = b2[hb * 16 + e15];
    }

    int wid = blockIdx.x * 4 + wsub;
    int nw = gridDim.x * 4;
    int ntiles = (n_edges + 15) >> 4;

    for (int t = wid; t < ntiles; t += nw) {
        int base = t << 4;
        // ---- stage 16 edge rows (fp32, lane = feature channel) ----
        for (int i = 0; i < 16; ++i) {
            int e = base + i;
            if (e < n_edges) {
                int snd = senders[e];
                int rcv = receivers[e];
                float s = x[(size_t)snd * 64 + lane];
                float r = x[(size_t)rcv * 64 + lane];
                if constexpr (KIN == 192) {
                    float p = wave_ln(eraw[(size_t)e * 64 + lane], plns, plnb);
                    Aw[i * PAD0 + lane] = p;
                    Aw[i * PAD0 + 64 + lane] = s;
                    Aw[i * PAD0 + 128 + lane] = r;
                } else {
                    Aw[i * PAD0 + lane] = s;
                    Aw[i * PAD0 + 64 + lane] = r;
                }
            }
        }
        // ---- layer 1 ----
        f32x4 acc[4];
#pragma unroll
        for (int hb = 0; hb < 4; ++hb)
            acc[hb] = (f32x4){bv0[hb], bv0[hb], bv0[hb], bv0[hb]};
        mfma_layer<KC0>(Aw, PAD0, B0h, B0m, B0l, lane, acc);
#pragma unroll
        for (int hb = 0; hb < 4; ++hb)
#pragma unroll
            for (int r = 0; r < 4; ++r)
                Av[(4 * l4 + r) * PAD1 + hb * 16 + e15] = gelu(acc[hb][r]);
        // ---- layer 2 ----
#pragma unroll
        for (int hb = 0; hb < 4; ++hb)
            acc[hb] = (f32x4){bv1[hb], bv1[hb], bv1[hb], bv1[hb]};
        mfma_layer<2>(Av, PAD1, B1h, B1m, B1l, lane, acc);
#pragma unroll
        for (int hb = 0; hb < 4; ++hb)
#pragma unroll
            for (int r = 0; r < 4; ++r)
                Av[(4 * l4 + r) * PAD1 + hb * 16 + e15] = gelu(acc[hb][r]);
        // ---- layer 3 (no act) -> raw edge store ----
#pragma unroll
        for (int hb = 0; hb < 4; ++hb)
            acc[hb] = (f32x4){bv2[hb], bv2[hb], bv2[hb], bv2[hb]};
        mfma_layer<2>(Av, PAD1, B2h, B2m, B2l, lane, acc);
#pragma unroll
        for (int hb = 0; hb < 4; ++hb)
#pragma unroll
            for (int r = 0; r < 4; ++r) {
                int e = base + 4 * l4 + r;
                if (e < n_edges)
                    eraw[(size_t)e * 64 + hb * 16 + e15] = acc[hb][r];
            }
    }
}

// ---------------------------------------------------------------------------
// Node MLP via MFMA: CSR gather-sum -> [x, received] (K=128) -> 3 layers -> LN.
__global__ __launch_bounds__(256) void k_node_mfma(
    const float* __restrict__ x, const float* __restrict__ eraw,
    const int* __restrict__ row_start, const int* __restrict__ elist,
    const ushort* __restrict__ B0h, const ushort* __restrict__ B0m,
    const ushort* __restrict__ B0l, const ushort* __restrict__ B1h,
    const ushort* __restrict__ B1m, const ushort* __restrict__ B1l,
    const ushort* __restrict__ B2h, const ushort* __restrict__ B2m,
    const ushort* __restrict__ B2l, const float* __restrict__ b0,
    const float* __restrict__ b1, const float* __restrict__ b2,
    const float* __restrict__ ln_s, const float* __restrict__ ln_b,
    float* __restrict__ xout, int n) {
    constexpr int PAD0 = 136;
    constexpr int PAD1 = 72;
    __shared__ float As[4][16 * PAD0];
    __shared__ float Aa[4][16 * PAD1];
    int tid = threadIdx.x;
    int lane = tid & 63;
    int wsub = tid >> 6;
    float* Aw = As[wsub];
    float* Av = Aa[wsub];
    int e15 = lane & 15, l4 = lane >> 4;

    float bv0[4], bv1[4], bv2[4], lnsv[4], lnbv[4];
#pragma unroll
    for (int hb = 0; hb < 4; ++hb) {
        bv0[hb] = b0[hb * 16 + e15];
        bv1[hb] = b1[hb * 16 + e15];
        bv2[hb] = b2[hb * 16 + e15];
        lnsv[hb] = ln_s[hb * 16 + e15];
        lnbv[hb] = ln_b[hb * 16 + e15];
    }

    int wid = blockIdx.x * 4 + wsub;
    int nw = gridDim.x * 4;
    int ntiles = (n + 15) >> 4;

    for (int t = wid; t < ntiles; t += nw) {
        int base = t << 4;
        for (int i = 0; i < 16; ++i) {
            int v = base + i;
            if (v < n) {
                float xv = x[(size_t)v * 64 + lane];
                int i0 = row_start[v], i1 = row_start[v + 1];
                float rv = 0.f, rv2 = 0.f;
                int ii = i0;
                for (; ii + 1 < i1; ii += 2) {
                    rv += eraw[(size_t)elist[ii] * 64 + lane];
                    rv2 += eraw[(size_t)elist[ii + 1] * 64 + lane];
                }
                if (ii < i1) rv += eraw[(size_t)elist[ii] * 64 + lane];
                rv += rv2;
                Aw[i * PAD0 + lane] = xv;
                Aw[i * PAD0 + 64 + lane] = rv;
            }
        }
        f32x4 acc[4];
#pragma unroll
        for (int hb = 0; hb < 4; ++hb)
            acc[hb] = (f32x4){bv0[hb], bv0[hb], bv0[hb], bv0[hb]};
        mfma_layer<4>(Aw, PAD0, B0h, B0m, B0l, lane, acc);
#pragma unroll
        for (int hb = 0; hb < 4; ++hb)
#pragma unroll
            for (int r = 0; r < 4; ++r)
                Av[(4 * l4 + r) * PAD1 + hb * 16 + e15] = gelu(acc[hb][r]);
#pragma unroll
        for (int hb = 0; hb < 4; ++hb)
            acc[hb] = (f32x4){bv1[hb], bv1[hb], bv1[hb], bv1[hb]};
        mfma_layer<2>(Av, PAD1, B1h, B1m, B1l, lane, acc);
#pragma unroll
        for (int hb = 0; hb < 4; ++hb)
#pragma unroll
            for (int r = 0; r < 4; ++r)
                Av[(4 * l4 + r) * PAD1 + hb * 16 + e15] = gelu(acc[hb][r]);
#pragma unroll
        for (int hb = 0; hb < 4; ++hb)
            acc[hb] = (f32x4){bv2[hb], bv2[hb], bv2[hb], bv2[hb]};
        mfma_layer<2>(Av, PAD1, B2h, B2m, B2l, lane, acc);
        // LayerNorm across h: node row m = 4*l4+r lives in the 16-lane group.
        float s1[4] = {0.f, 0.f, 0.f, 0.f}, s2[4] = {0.f, 0.f, 0.f, 0.f};
#pragma unroll
        for (int hb = 0; hb < 4; ++hb)
#pragma unroll
            for (int r = 0; r < 4; ++r) {
                float vv = acc[hb][r];
                s1[r] += vv;
                s2[r] += vv * vv;
            }
#pragma unroll
        for (int m = 1; m <= 8; m <<= 1)
#pragma unroll
            for (int r = 0; r < 4; ++r) {
                s1[r] += __shfl_xor(s1[r], m, 64);
                s2[r] += __shfl_xor(s2[r], m, 64);
            }
#pragma unroll
        for (int r = 0; r < 4; ++r) {
            int v = base + 4 * l4 + r;
            if (v < n) {
                float mu = s1[r] * (1.f / 64.f);
                float var = s2[r] * (1.f / 64.f) - mu * mu;
                float rs = rsqrtf(var + 1e-6f);
#pragma unroll
                for (int hb = 0; hb < 4; ++hb)
                    xout[(size_t)v * 64 + hb * 16 + e15] =
                        (acc[hb][r] - mu) * rs * lnsv[hb] + lnbv[hb];
            }
        }
    }
}

// ---------------------------------------------------------------------------
// CSR construction (unchanged, validated r10)
__global__ void k_hist(const int* __restrict__ receivers, int* __restrict__ cnt,
                       int nE) {
    int e = blockIdx.x * blockDim.x + threadIdx.x;
    if (e < nE) atomicAdd(&cnt[receivers[e]], 1);
}

__global__ void k_scan1(const int* __restrict__ cnt, int* __restrict__ bsum,
                        int n) {
    __shared__ int sb[256];
    int t = threadIdx.x;
    int i = blockIdx.x * 256 + t;
    sb[t] = (i < n) ? cnt[i] : 0;
    __syncthreads();
    for (int off = 128; off; off >>= 1) {
        if (t < off) sb[t] += sb[t + off];
        __syncthreads();
    }
    if (t == 0) bsum[blockIdx.x] = sb[0];
}

__global__ void k_scan2(int* __restrict__ bsum, int nb) {
    __shared__ int sb[256];
    int t = threadIdx.x;
    int v = (t < nb) ? bsum[t] : 0;
    sb[t] = v;
    __syncthreads();
    for (int off = 1; off < 256; off <<= 1) {
        int add = (t >= off) ? sb[t - off] : 0;
        __syncthreads();
        sb[t] += add;
        __syncthreads();
    }
    if (t < nb) bsum[t] = sb[t] - v;  // exclusive
}

__global__ void k_scan3(const int* __restrict__ cnt, const int* __restrict__ bsum,
                        int* __restrict__ row_start, int* __restrict__ cursor,
                        int n, int nE) {
    __shared__ int sb[256];
    int t = threadIdx.x;
    int i = blockIdx.x * 256 + t;
    int v = (i < n) ? cnt[i] : 0;
    sb[t] = v;
    __syncthreads();
    for (int off = 1; off < 256; off <<= 1) {
        int add = (t >= off) ? sb[t - off] : 0;
        __syncthreads();
        sb[t] += add;
        __syncthreads();
    }
    if (i < n) {
        int ex = bsum[blockIdx.x] + sb[t] - v;
        row_start[i] = ex;
        cursor[i] = ex;
    }
    if (i == n - 1) row_start[n] = nE;
}

__global__ void k_fill(const int* __restrict__ receivers, int* __restrict__ cursor,
                       int* __restrict__ elist, int nE) {
    int e = blockIdx.x * blockDim.x + threadIdx.x;
    if (e < nE) {
        int r = receivers[e];
        int p = atomicAdd(&cursor[r], 1);
        elist[p] = e;
    }
}

// ---------------------------------------------------------------------------
__global__ void k_embed(const float* __restrict__ nodes,
                        const float* __restrict__ W, const float* __restrict__ b,
                        float* __restrict__ x, int n) {
    int lane = threadIdx.x & 63;
    int wid = blockIdx.x * 4 + (threadIdx.x >> 6);
    int nw = gridDim.x * 4;
    float wcol[7];
#pragma unroll
    for (int k = 0; k < 7; ++k) wcol[k] = W[k * 64 + lane];
    float bh = b[lane];
    for (int v = wid; v < n; v += nw) {
        float acc = bh;
#pragma unroll
        for (int k = 0; k < 7; ++k) acc = fmaf(nodes[v * 7 + k], wcol[k], acc);
        x[(size_t)v * 64 + lane] = acc;
    }
}

__global__ void k_mean(const float* __restrict__ x, float* __restrict__ agg,
                       int n) {
    int t = threadIdx.x;
    int h = t & 63;
    int sub = t >> 6;
    float s = 0.f;
    for (int v = blockIdx.x * 4 + sub; v < n; v += gridDim.x * 4)
        s += x[(size_t)v * 64 + h];
    __shared__ float buf[256];
    buf[t] = s;
    __syncthreads();
    if (t < 64) {
        float tot = buf[t] + buf[t + 64] + buf[t + 128] + buf[t + 192];
        atomicAdd(&agg[h], tot);
    }
}

__global__ void k_readout(const float* __restrict__ agg,
                          const float* __restrict__ W1, const float* __restrict__ b1,
                          const float* __restrict__ W2, const float* __restrict__ b2,
                          const float* __restrict__ W3, const float* __restrict__ b3,
                          const float* __restrict__ W4, const float* __restrict__ b4,
                          float* __restrict__ out, float inv_n) {
    __shared__ float sA[64], sH1[256], sH2[128], sH3[128];
    int t = threadIdx.x;
    if (t < 64) sA[t] = agg[t] * inv_n;
    __syncthreads();
    {
        float acc = b1[t];
#pragma unroll
        for (int k = 0; k < 64; ++k) acc = fmaf(sA[k], W1[k * 256 + t], acc);
        sH1[t] = gelu(acc);
    }
    __syncthreads();
    if (t < 128) {
        float acc = b2[t];
        for (int k = 0; k < 256; ++k) acc = fmaf(sH1[k], W2[k * 128 + t], acc);
        sH2[t] = gelu(acc);
    }
    __syncthreads();
    if (t < 128) {
        float acc = b3[t];
        for (int k = 0; k < 128; ++k) acc = fmaf(sH2[k], W3[k * 128 + t], acc);
        sH3[t] = gelu(acc);
    }
    __syncthreads();
    if (t < 64) {
        float p = fmaf(sH3[t], W4[t], sH3[t + 64] * W4[t + 64]);
#pragma unroll
        for (int m = 32; m; m >>= 1) p += __shfl_xor(p, m, 64);
        if (t == 0) out[0] = p + b4[0];
    }
}

// ---------------------------------------------------------------------------
extern "C" void kernel_launch(void* const* d_in, const int* in_sizes, int n_in,
                              void* d_out, int out_size, void* d_ws,
                              size_t ws_size, hipStream_t stream) {
    const float* nodes = (const float*)d_in[0];
    const int* senders = (const int*)d_in[1];
    const int* receivers = (const int*)d_in[2];
    const float* W_emb = (const float*)d_in[3];
    const float* b_emb = (const float*)d_in[4];
    const float* eW0_first = (const float*)d_in[5];
    const float* eW0_rest = (const float*)d_in[6];
    const float* eW_hid = (const float*)d_in[7];
    const float* eb = (const float*)d_in[8];
    const float* nW0 = (const float*)d_in[9];
    const float* nW_hid = (const float*)d_in[10];
    const float* nb = (const float*)d_in[11];
    const float* ln_ns = (const float*)d_in[12];
    const float* ln_nb = (const float*)d_in[13];
    const float* ln_es = (const float*)d_in[14];
    const float* ln_eb = (const float*)d_in[15];
    const float* rW1 = (const float*)d_in[16];
    const float* rb1 = (const float*)d_in[17];
    const float* rW2 = (const float*)d_in[18];
    const float* rb2 = (const float*)d_in[19];
    const float* rW3 = (const float*)d_in[20];
    const float* rb3 = (const float*)d_in[21];
    const float* rW4 = (const float*)d_in[22];
    const float* rb4 = (const float*)d_in[23];

    const int N = in_sizes[0] / 7;  // 50000
    const int E = in_sizes[1];      // 800000

    float* ws = (float*)d_ws;
    float* eraw = ws;                          // E*64
    float* xa = eraw + (size_t)E * 64;         // N*64
    float* xb = xa + (size_t)N * 64;           // N*64
    float* agg = xb + (size_t)N * 64;          // 64
    int* cnt = (int*)(agg + 64);               // N
    int* row_start = cnt + N;                  // N+1
    int* cursor = row_start + N + 1;           // N
    int* elist = cursor + N;                   // E
    int* bsum = elist + E;                     // 256
    // frag-ordered split weights (u16): hi/mid/lo, 106496 elems each
    const int WTOT = 106496;
    ushort* wfh = (ushort*)(bsum + 256);
    ushort* wfm = wfh + WTOT;
    ushort* wfl = wfm + WTOT;

    // per-matrix frag offsets (u16 elems)
    const int OFF_E0 = 0;                         // eW0_first  K=128 (8192)
    const int OFF_E1 = 8192;                      // eW0_rest[0] K=192 (12288)
    const int OFF_E2 = 20480;                     // eW0_rest[1] K=192
    const int OFF_EH = 32768;                     // eW_hid[s][l] K=64 (4096 ea)
    const int OFF_N0 = 57344;                     // nW0[s] K=128 (8192 ea)
    const int OFF_NH = 81920;                     // nW_hid[s][l] K=64 (4096 ea)

    // ---- weight prep (re-run every call; graph-safe) ----
    k_prep<<<32, 256, 0, stream>>>(eW0_first, wfh + OFF_E0, wfm + OFF_E0,
                                   wfl + OFF_E0, 128);
    k_prep<<<48, 256, 0, stream>>>(eW0_rest, wfh + OFF_E1, wfm + OFF_E1,
                                   wfl + OFF_E1, 192);
    k_prep<<<48, 256, 0, stream>>>(eW0_rest + (size_t)192 * 64, wfh + OFF_E2,
                                   wfm + OFF_E2, wfl + OFF_E2, 192);
    for (int i = 0; i < 6; ++i) {
        k_prep<<<16, 256, 0, stream>>>(eW_hid + (size_t)i * 4096,
                                       wfh + OFF_EH + i * 4096,
                                       wfm + OFF_EH + i * 4096,
                                       wfl + OFF_EH + i * 4096, 64);
        k_prep<<<16, 256, 0, stream>>>(nW_hid + (size_t)i * 4096,
                                       wfh + OFF_NH + i * 4096,
                                       wfm + OFF_NH + i * 4096,
                                       wfl + OFF_NH + i * 4096, 64);
    }
    for (int s = 0; s < 3; ++s)
        k_prep<<<32, 256, 0, stream>>>(nW0 + (size_t)s * 8192,
                                       wfh + OFF_N0 + s * 8192,
                                       wfm + OFF_N0 + s * 8192,
                                       wfl + OFF_N0 + s * 8192, 128);

    const int nb_scan = (N + 255) / 256;

    // ---- CSR build ----
    hipMemsetAsync(cnt, 0, (size_t)N * sizeof(int), stream);
    k_hist<<<(E + 255) / 256, 256, 0, stream>>>(receivers, cnt, E);
    k_scan1<<<nb_scan, 256, 0, stream>>>(cnt, bsum, N);
    k_scan2<<<1, 256, 0, stream>>>(bsum, nb_scan);
    k_scan3<<<nb_scan, 256, 0, stream>>>(cnt, bsum, row_start, cursor, N, E);
    k_fill<<<(E + 255) / 256, 256, 0, stream>>>(receivers, cursor, elist, E);

    k_embed<<<512, 256, 0, stream>>>(nodes, W_emb, b_emb, xa, N);

    float* xc = xa;
    float* xn = xb;
    for (int s = 0; s < 3; ++s) {
        int h1 = OFF_EH + (s * 2 + 0) * 4096;
        int h2 = OFF_EH + (s * 2 + 1) * 4096;
        const float* eb0 = eb + (s * 3 + 0) * 64;
        const float* eb1 = eb + (s * 3 + 1) * 64;
        const float* eb2 = eb + (s * 3 + 2) * 64;
        if (s == 0) {
            k_edge_mfma<128><<<1024, 256, 0, stream>>>(
                xc, eraw, senders, receivers, wfh + OFF_E0, wfm + OFF_E0,
                wfl + OFF_E0, wfh + h1, wfm + h1, wfl + h1, wfh + h2, wfm + h2,
                wfl + h2, eb0, eb1, eb2, nullptr, nullptr, E);
        } else {
            int w0 = (s == 1) ? OFF_E1 : OFF_E2;
            k_edge_mfma<192><<<1024, 256, 0, stream>>>(
                xc, eraw, senders, receivers, wfh + w0, wfm + w0, wfl + w0,
                wfh + h1, wfm + h1, wfl + h1, wfh + h2, wfm + h2, wfl + h2,
                eb0, eb1, eb2, ln_es + (s - 1) * 64, ln_eb + (s - 1) * 64, E);
        }
        int n1 = OFF_NH + (s * 2 + 0) * 4096;
        int n2 = OFF_NH + (s * 2 + 1) * 4096;
        int n0 = OFF_N0 + s * 8192;
        k_node_mfma<<<512, 256, 0, stream>>>(
            xc, eraw, row_start, elist, wfh + n0, wfm + n0, wfl + n0, wfh + n1,
            wfm + n1, wfl + n1, wfh + n2, wfm + n2, wfl + n2,
            nb + (s * 3 + 0) * 64, nb + (s * 3 + 1) * 64, nb + (s * 3 + 2) * 64,
            ln_ns + s * 64, ln_nb + s * 64, xn, N);
        float* tmp = xc;
        xc = xn;
        xn = tmp;
    }

    hipMemsetAsync(agg, 0, 64 * sizeof(float), stream);
    k_mean<<<256, 256, 0, stream>>>(xc, agg, N);
    k_readout<<<1, 256, 0, stream>>>(agg, rW1, rb1, rW2, rb2, rW3, rb3, rW4,
                                     rb4, (float*)d_out, 1.0f / (float)N);
}